// Round 10
// baseline (1489.705 us; speedup 1.0000x reference)
//
#include <hip/hip_runtime.h>
#include <math.h>

// BracketNet: ctx_{s+1} = GELU_exact(Wc·ctx_s + (b + Wx·x_s)); out_s = x_s + ctx_{s+1}
// pass1: z = b + Wx·x, parallel, one wave per (b,h,128-s chunk), LDS-broadcast
//        GEMV (occupancy 8 waves/SIMD hides all latency). ~186 us measured.
// pass2: serial chain; one wave runs TWO same-head chains (b, b+1) interleaved
//        so chain A's readlane->fma hazard bubbles are filled by chain B's
//        independent ops (1 wave/SIMD -> nothing else fills them). Shared
//        pinned 64-VGPR weight set (same head => same Wc).
//
// Broadcast-primitive scoreboard (cyc/step, measured r7-r9): readlane 808 <
// bpermute+MFMA 1078 < LDS write->read_b128 1100. Readlane stalls are ~550
// cyc of hazard bubbles => interleave a second chain rather than switch
// primitive.

typedef float f32x4 __attribute__((ext_vector_type(4)));

#define S_LEN 2048
#define B_SZ  64
#define D_SZ  512
#define DIM   64
#define STRIDE ((size_t)(B_SZ * D_SZ))   // floats between consecutive s

// Branchless exact-GELU: 0.5*y*(1+erf(y/sqrt2)), erf via A&S 7.1.26 (|eps|<=1.5e-7).
__device__ __forceinline__ float gelu_exact(float y) {
    const float ax = fabsf(y) * 0.70710678118654752440f;     // |y|/sqrt(2)
    const float t  = __builtin_amdgcn_rcpf(fmaf(0.3275911f, ax, 1.0f));
    float p = fmaf(1.061405429f, t, -1.453152027f);
    p = fmaf(p, t, 1.421413741f);
    p = fmaf(p, t, -0.284496736f);
    p = fmaf(p, t, 0.254829592f);
    p *= t;
    const float e = __builtin_amdgcn_exp2f(-ax * ax * 1.44269504088896f);
    float er = fmaf(-p, e, 1.0f);                            // erf(|x|)
    er = copysignf(er, y);
    return 0.5f * y * (1.0f + er);
}

// ---------------- Pass 1 (unchanged from round 9): LDS-broadcast GEMV.
__device__ __forceinline__ float gemv64(const f32x4* vv, const f32x4 (&w)[16],
                                        float base) {
    float a0 = base, a1 = 0.f, a2 = 0.f, a3 = 0.f;
    float a4 = 0.f, a5 = 0.f, a6 = 0.f, a7 = 0.f;
#pragma unroll
    for (int j = 0; j < 16; j += 2) {
        const f32x4 u0 = vv[j], u1 = vv[j + 1];
        a0 = fmaf(w[j].x,     u0.x, a0);
        a1 = fmaf(w[j].y,     u0.y, a1);
        a2 = fmaf(w[j].z,     u0.z, a2);
        a3 = fmaf(w[j].w,     u0.w, a3);
        a4 = fmaf(w[j + 1].x, u1.x, a4);
        a5 = fmaf(w[j + 1].y, u1.y, a5);
        a6 = fmaf(w[j + 1].z, u1.z, a6);
        a7 = fmaf(w[j + 1].w, u1.w, a7);
    }
    return ((a0 + a1) + (a2 + a3)) + ((a4 + a5) + (a6 + a7));
}

__global__ __launch_bounds__(64, 1) void bracket_pass1(
    const float* __restrict__ src, const float* __restrict__ W,
    const float* __restrict__ bias, float* __restrict__ zout)
{
    const int lane = threadIdx.x;
    const int ck   = blockIdx.x >> 9;          // 0..15 (128 s each)
    const int bb   = (blockIdx.x >> 3) & 63;
    const int hh   = blockIdx.x & 7;

    f32x4 w[16];
    {
        const float* wb = W + (size_t)(hh * DIM + lane) * (2 * DIM) + DIM;
#pragma unroll
        for (int i = 0; i < 16; ++i)
            asm volatile("global_load_dwordx4 %0, %1, off offset:%2"
                         : "=v"(w[i]) : "v"(wb), "i"(16 * i));
    }
    asm volatile("s_waitcnt vmcnt(0)" ::: "memory");
    __builtin_amdgcn_sched_barrier(0);

    const float bv = bias[hh * DIM + lane];

    __shared__ __align__(16) float xsl[2][DIM];   // 512 B ping-pong

    const float* sp = src  + (size_t)(ck * 128) * STRIDE + (size_t)bb * D_SZ + hh * DIM + lane;
    float*       zp = zout + (size_t)(ck * 128) * STRIDE + (size_t)bb * D_SZ + hh * DIM + lane;

    float x0 = sp[0], x1 = sp[STRIDE];
    const float* pp    = sp + 2 * STRIDE;
    const float* plast = sp + 127 * STRIDE;

#define P1STEP(cur, xc)                                                       \
    do {                                                                      \
        xsl[cur][lane] = xc;                   /* ds_write_b32 */             \
        const float xn = *pp;                  /* fire-and-forget prefetch */ \
        pp = (pp < plast) ? (pp + STRIDE) : plast;                            \
        const float y = gemv64((const f32x4*)xsl[cur], w, bv);                \
        *zp = y;                                                              \
        zp += STRIDE;                                                         \
        xc = xn;                                                              \
    } while (0)

    for (int i = 0; i < 128; i += 2) {
        P1STEP(0, x0);
        P1STEP(1, x1);
    }
#undef P1STEP
}

// ---------------- Pass 2: two same-head chains per wave, readlane-GEMV.
#define RL2(k, comp, n)                                                       \
    a0##n = fmaf(__int_as_float(__builtin_amdgcn_readlane(gi0, (k))),         \
                 w[(k) >> 2].comp, a0##n);                                    \
    a1##n = fmaf(__int_as_float(__builtin_amdgcn_readlane(gi1, (k))),         \
                 w[(k) >> 2].comp, a1##n);
#define GG(m)                                                                 \
    RL2(8 * m + 0, x, 0) RL2(8 * m + 1, y, 1) RL2(8 * m + 2, z, 2)            \
    RL2(8 * m + 3, w, 3) RL2(8 * m + 4, x, 4) RL2(8 * m + 5, y, 5)            \
    RL2(8 * m + 6, z, 6) RL2(8 * m + 7, w, 7)

__global__ __launch_bounds__(64, 1) void bracket_pass2(
    const float* __restrict__ src, const float* __restrict__ W,
    float* __restrict__ out)   // out holds z on entry; overwritten with result
{
    const int lane = threadIdx.x;
    const int hh   = blockIdx.x & 7;              // head (shared weights)
    const int b0   = (blockIdx.x >> 3) * 2;       // chains (b0,hh) and (b0+1,hh)

    // Wc row: 16 float4 = 64 VGPRs, pinned (volatile asm, non-rematerializable).
    f32x4 w[16];
    {
        const float* wb = W + (size_t)(hh * DIM + lane) * (2 * DIM);
#pragma unroll
        for (int i = 0; i < 16; ++i)
            asm volatile("global_load_dwordx4 %0, %1, off offset:%2"
                         : "=v"(w[i]) : "v"(wb), "i"(16 * i));
    }
    asm volatile("s_waitcnt vmcnt(0)" ::: "memory");
    __builtin_amdgcn_sched_barrier(0);

    const float* sp0 = src + (size_t)b0 * D_SZ + hh * DIM + lane;
    const float* sp1 = sp0 + D_SZ;
    float*       op0 = out + (size_t)b0 * D_SZ + hh * DIM + lane;
    float*       op1 = op0 + D_SZ;

    // Depth-4 prefetch pipelines per chain (x from src, z from out).
    float xa[4], za[4], xb[4], zb[4];
#pragma unroll
    for (int i = 0; i < 4; ++i) {
        xa[i] = sp0[(size_t)i * STRIDE]; za[i] = op0[(size_t)i * STRIDE];
        xb[i] = sp1[(size_t)i * STRIDE]; zb[i] = op1[(size_t)i * STRIDE];
    }
    const float* px0 = sp0 + 4 * STRIDE;
    const float* pz0 = op0 + 4 * STRIDE;
    const float* px1 = sp1 + 4 * STRIDE;
    const float* pz1 = op1 + 4 * STRIDE;

    float gA = 0.0f, gB = 0.0f;   // ctx_0 = 0 for both chains

#define STEP2(zai, xai, zbi, xbi)                                             \
    do {                                                                      \
        const int gi0 = __float_as_int(gA);                                   \
        const int gi1 = __float_as_int(gB);                                   \
        float a00 = (zai), a01 = 0.f, a02 = 0.f, a03 = 0.f;                   \
        float a04 = 0.f, a05 = 0.f, a06 = 0.f, a07 = 0.f;                     \
        float a10 = (zbi), a11 = 0.f, a12 = 0.f, a13 = 0.f;                   \
        float a14 = 0.f, a15 = 0.f, a16 = 0.f, a17 = 0.f;                     \
        GG(0); GG(1); GG(2); GG(3); GG(4); GG(5); GG(6); GG(7);               \
        const float y0 = ((a00 + a01) + (a02 + a03)) + ((a04 + a05) + (a06 + a07)); \
        const float y1 = ((a10 + a11) + (a12 + a13)) + ((a14 + a15) + (a16 + a17)); \
        gA = gelu_exact(y0);                                                  \
        gB = gelu_exact(y1);                                                  \
        *op0 = (xai) + gA; op0 += STRIDE;                                     \
        *op1 = (xbi) + gB; op1 += STRIDE;                                     \
    } while (0)

    // Main loop: 511 x 4 = 2044 steps with prefetch (s+4 <= 2047 always).
    for (int s = 0; s < S_LEN - 4; s += 4) {
#pragma unroll
        for (int i = 0; i < 4; ++i) {
            const float xn0 = *px0, zn0 = *pz0, xn1 = *px1, zn1 = *pz1;
            px0 += STRIDE; pz0 += STRIDE; px1 += STRIDE; pz1 += STRIDE;
            STEP2(za[i], xa[i], zb[i], xb[i]);
            xa[i] = xn0; za[i] = zn0; xb[i] = xn1; zb[i] = zn1;
        }
    }
    // Epilogue: last 4 steps, no prefetch.
    STEP2(za[0], xa[0], zb[0], xb[0]);
    STEP2(za[1], xa[1], zb[1], xb[1]);
    STEP2(za[2], xa[2], zb[2], xb[2]);
    STEP2(za[3], xa[3], zb[3], xb[3]);
#undef STEP2
}

extern "C" void kernel_launch(void* const* d_in, const int* in_sizes, int n_in,
                              void* d_out, int out_size, void* d_ws, size_t ws_size,
                              hipStream_t stream) {
    const float* src = (const float*)d_in[0];
    const float* W   = (const float*)d_in[1];
    const float* b   = (const float*)d_in[2];
    float* out       = (float*)d_out;

    hipLaunchKernelGGL(bracket_pass1, dim3(B_SZ * 8 * 16), dim3(64), 0, stream,
                       src, W, b, out);
    hipLaunchKernelGGL(bracket_pass2, dim3(B_SZ * 8 / 2), dim3(64), 0, stream,
                       src, W, out);
}

// Round 11
// 753.236 us; speedup vs baseline: 1.9777x; 1.9777x over previous
//
#include <hip/hip_runtime.h>
#include <math.h>

// BracketNet: ctx_{s+1} = GELU_exact(Wc·ctx_s + (b + Wx·x_s)); out_s = x_s + ctx_{s+1}
// pass1: z = b + Wx·x, parallel, one wave per (b,h,128-s chunk), LDS-broadcast
//        GEMV at 8 waves/SIMD (~186 us measured, round 9).
// pass2: serial chain, one wave per (b,h), readlane-GEMV with HAZARD-BROKEN
//        scheduling: 16 readlanes batched, sched_barrier(0), then 16 fmas.
//
// Round-10 lesson: readlane->fma def-use ADJACENCY costs ~4 hazard wait-states
// per pair (~480 of 808 cyc/step). Chain-pairing didn't break it because the
// macro still emitted fma right after its readlane. Fix = batch the (mutually
// independent) readlanes 16 at a time and fence the scheduler so no fma is
// issued within 15 instructions of its defining readlane.

typedef float f32x4 __attribute__((ext_vector_type(4)));

#define S_LEN 2048
#define B_SZ  64
#define D_SZ  512
#define DIM   64
#define STRIDE ((size_t)(B_SZ * D_SZ))   // floats between consecutive s

// Branchless exact-GELU: 0.5*y*(1+erf(y/sqrt2)), erf via A&S 7.1.26 (|eps|<=1.5e-7).
__device__ __forceinline__ float gelu_exact(float y) {
    const float ax = fabsf(y) * 0.70710678118654752440f;     // |y|/sqrt(2)
    const float t  = __builtin_amdgcn_rcpf(fmaf(0.3275911f, ax, 1.0f));
    float p = fmaf(1.061405429f, t, -1.453152027f);
    p = fmaf(p, t, 1.421413741f);
    p = fmaf(p, t, -0.284496736f);
    p = fmaf(p, t, 0.254829592f);
    p *= t;
    const float e = __builtin_amdgcn_exp2f(-ax * ax * 1.44269504088896f);
    float er = fmaf(-p, e, 1.0f);                            // erf(|x|)
    er = copysignf(er, y);
    return 0.5f * y * (1.0f + er);
}

// ---------------- Pass 1 (unchanged from round 9): LDS-broadcast GEMV.
__device__ __forceinline__ float gemv64(const f32x4* vv, const f32x4 (&w)[16],
                                        float base) {
    float a0 = base, a1 = 0.f, a2 = 0.f, a3 = 0.f;
    float a4 = 0.f, a5 = 0.f, a6 = 0.f, a7 = 0.f;
#pragma unroll
    for (int j = 0; j < 16; j += 2) {
        const f32x4 u0 = vv[j], u1 = vv[j + 1];
        a0 = fmaf(w[j].x,     u0.x, a0);
        a1 = fmaf(w[j].y,     u0.y, a1);
        a2 = fmaf(w[j].z,     u0.z, a2);
        a3 = fmaf(w[j].w,     u0.w, a3);
        a4 = fmaf(w[j + 1].x, u1.x, a4);
        a5 = fmaf(w[j + 1].y, u1.y, a5);
        a6 = fmaf(w[j + 1].z, u1.z, a6);
        a7 = fmaf(w[j + 1].w, u1.w, a7);
    }
    return ((a0 + a1) + (a2 + a3)) + ((a4 + a5) + (a6 + a7));
}

__global__ __launch_bounds__(64, 1) void bracket_pass1(
    const float* __restrict__ src, const float* __restrict__ W,
    const float* __restrict__ bias, float* __restrict__ zout)
{
    const int lane = threadIdx.x;
    const int ck   = blockIdx.x >> 9;          // 0..15 (128 s each)
    const int bb   = (blockIdx.x >> 3) & 63;
    const int hh   = blockIdx.x & 7;

    f32x4 w[16];
    {
        const float* wb = W + (size_t)(hh * DIM + lane) * (2 * DIM) + DIM;
#pragma unroll
        for (int i = 0; i < 16; ++i)
            asm volatile("global_load_dwordx4 %0, %1, off offset:%2"
                         : "=v"(w[i]) : "v"(wb), "i"(16 * i));
    }
    asm volatile("s_waitcnt vmcnt(0)" ::: "memory");
    __builtin_amdgcn_sched_barrier(0);

    const float bv = bias[hh * DIM + lane];

    __shared__ __align__(16) float xsl[2][DIM];   // 512 B ping-pong

    const float* sp = src  + (size_t)(ck * 128) * STRIDE + (size_t)bb * D_SZ + hh * DIM + lane;
    float*       zp = zout + (size_t)(ck * 128) * STRIDE + (size_t)bb * D_SZ + hh * DIM + lane;

    float x0 = sp[0], x1 = sp[STRIDE];
    const float* pp    = sp + 2 * STRIDE;
    const float* plast = sp + 127 * STRIDE;

#define P1STEP(cur, xc)                                                       \
    do {                                                                      \
        xsl[cur][lane] = xc;                   /* ds_write_b32 */             \
        const float xn = *pp;                  /* fire-and-forget prefetch */ \
        pp = (pp < plast) ? (pp + STRIDE) : plast;                            \
        const float y = gemv64((const f32x4*)xsl[cur], w, bv);                \
        *zp = y;                                                              \
        zp += STRIDE;                                                         \
        xc = xn;                                                              \
    } while (0)

    for (int i = 0; i < 128; i += 2) {
        P1STEP(0, x0);
        P1STEP(1, x1);
    }
#undef P1STEP
}

// ---------------- Pass 2: serial chain, hazard-broken readlane GEMV.
// 16 independent readlanes -> sched_barrier -> 16 fmas (def-use distance >=15).
#define RL16(m)                                                               \
    do {                                                                      \
        const int t0  = __builtin_amdgcn_readlane(gi, 16 * m + 0);            \
        const int t1  = __builtin_amdgcn_readlane(gi, 16 * m + 1);            \
        const int t2  = __builtin_amdgcn_readlane(gi, 16 * m + 2);            \
        const int t3  = __builtin_amdgcn_readlane(gi, 16 * m + 3);            \
        const int t4  = __builtin_amdgcn_readlane(gi, 16 * m + 4);            \
        const int t5  = __builtin_amdgcn_readlane(gi, 16 * m + 5);            \
        const int t6  = __builtin_amdgcn_readlane(gi, 16 * m + 6);            \
        const int t7  = __builtin_amdgcn_readlane(gi, 16 * m + 7);            \
        const int t8  = __builtin_amdgcn_readlane(gi, 16 * m + 8);            \
        const int t9  = __builtin_amdgcn_readlane(gi, 16 * m + 9);            \
        const int t10 = __builtin_amdgcn_readlane(gi, 16 * m + 10);           \
        const int t11 = __builtin_amdgcn_readlane(gi, 16 * m + 11);           \
        const int t12 = __builtin_amdgcn_readlane(gi, 16 * m + 12);           \
        const int t13 = __builtin_amdgcn_readlane(gi, 16 * m + 13);           \
        const int t14 = __builtin_amdgcn_readlane(gi, 16 * m + 14);           \
        const int t15 = __builtin_amdgcn_readlane(gi, 16 * m + 15);           \
        __builtin_amdgcn_sched_barrier(0);                                    \
        a0 = fmaf(__int_as_float(t0),  w[4 * m + 0].x, a0);                   \
        a1 = fmaf(__int_as_float(t1),  w[4 * m + 0].y, a1);                   \
        a2 = fmaf(__int_as_float(t2),  w[4 * m + 0].z, a2);                   \
        a3 = fmaf(__int_as_float(t3),  w[4 * m + 0].w, a3);                   \
        a4 = fmaf(__int_as_float(t4),  w[4 * m + 1].x, a4);                   \
        a5 = fmaf(__int_as_float(t5),  w[4 * m + 1].y, a5);                   \
        a6 = fmaf(__int_as_float(t6),  w[4 * m + 1].z, a6);                   \
        a7 = fmaf(__int_as_float(t7),  w[4 * m + 1].w, a7);                   \
        a0 = fmaf(__int_as_float(t8),  w[4 * m + 2].x, a0);                   \
        a1 = fmaf(__int_as_float(t9),  w[4 * m + 2].y, a1);                   \
        a2 = fmaf(__int_as_float(t10), w[4 * m + 2].z, a2);                   \
        a3 = fmaf(__int_as_float(t11), w[4 * m + 2].w, a3);                   \
        a4 = fmaf(__int_as_float(t12), w[4 * m + 3].x, a4);                   \
        a5 = fmaf(__int_as_float(t13), w[4 * m + 3].y, a5);                   \
        a6 = fmaf(__int_as_float(t14), w[4 * m + 3].z, a6);                   \
        a7 = fmaf(__int_as_float(t15), w[4 * m + 3].w, a7);                   \
    } while (0)

__global__ __launch_bounds__(64, 1) void bracket_pass2(
    const float* __restrict__ src, const float* __restrict__ W,
    float* __restrict__ out)   // out holds z on entry; overwritten with result
{
    const int lane = threadIdx.x;
    const int bb   = blockIdx.x >> 3;
    const int hh   = blockIdx.x & 7;

    // Wc row: 16 float4 = 64 VGPRs, pinned (volatile asm, non-rematerializable).
    f32x4 w[16];
    {
        const float* wb = W + (size_t)(hh * DIM + lane) * (2 * DIM);
#pragma unroll
        for (int i = 0; i < 16; ++i)
            asm volatile("global_load_dwordx4 %0, %1, off offset:%2"
                         : "=v"(w[i]) : "v"(wb), "i"(16 * i));
    }
    asm volatile("s_waitcnt vmcnt(0)" ::: "memory");
    __builtin_amdgcn_sched_barrier(0);

    const float* sp = src + (size_t)bb * D_SZ + hh * DIM + lane;
    float*       op = out + (size_t)bb * D_SZ + hh * DIM + lane;

    // Depth-8 prefetch pipelines (x from src, z from out).
    float xb[8], zb[8];
#pragma unroll
    for (int i = 0; i < 8; ++i) {
        xb[i] = sp[(size_t)i * STRIDE];
        zb[i] = op[(size_t)i * STRIDE];
    }
    const float* px  = sp + 8 * STRIDE;
    const float* pz  = op + 8 * STRIDE;
    const float* pxl = sp + (size_t)(S_LEN - 1) * STRIDE;
    const float* pzl = op + (size_t)(S_LEN - 1) * STRIDE;

    float g = 0.0f;   // ctx_0 = 0

    for (int s = 0; s < S_LEN; s += 8) {
#pragma unroll
        for (int i = 0; i < 8; ++i) {
            const int gi = __float_as_int(g);
            float a0 = zb[i], a1 = 0.f, a2 = 0.f, a3 = 0.f;
            float a4 = 0.f, a5 = 0.f, a6 = 0.f, a7 = 0.f;
            RL16(0); RL16(1); RL16(2); RL16(3);
            const float y = ((a0 + a1) + (a2 + a3)) + ((a4 + a5) + (a6 + a7));
            g = gelu_exact(y);

            *op = xb[i] + g;                     // out = x + ctx (off-path)
            op += STRIDE;

            // Prefetch s+8 (off the critical path).
            xb[i] = *px;
            zb[i] = *pz;
            px = (px < pxl) ? px + STRIDE : pxl;
            pz = (pz < pzl) ? pz + STRIDE : pzl;
        }
    }
}

extern "C" void kernel_launch(void* const* d_in, const int* in_sizes, int n_in,
                              void* d_out, int out_size, void* d_ws, size_t ws_size,
                              hipStream_t stream) {
    const float* src = (const float*)d_in[0];
    const float* W   = (const float*)d_in[1];
    const float* b   = (const float*)d_in[2];
    float* out       = (float*)d_out;

    hipLaunchKernelGGL(bracket_pass1, dim3(B_SZ * 8 * 16), dim3(64), 0, stream,
                       src, W, b, out);
    hipLaunchKernelGGL(bracket_pass2, dim3(B_SZ * 8), dim3(64), 0, stream,
                       src, W, out);
}

// Round 13
// 740.508 us; speedup vs baseline: 2.0117x; 1.0172x over previous
//
#include <hip/hip_runtime.h>
#include <math.h>

// BracketNet: ctx_{s+1} = GELU_exact(Wc·ctx_s + (b + Wx·x_s)); out_s = x_s + ctx_{s+1}
// pass1: z = b + Wx·x, parallel, LDS-broadcast GEMV at 8 waves/SIMD (~186 us).
// pass2: serial chain, one wave per (b,h). GEMV via f16-pair broadcast:
//        g packed to f16x2 (DPP row_shl:1 + cvt_pkrtz), 32 readlanes of pairs,
//        32 v_dot2_f32_f16 (2 MACs/inst, fp32 acc) against pre-packed f16x2
//        weights. 16-deep readlane batching + sched_barrier (round-11 lesson).
//
// Round-12 lessons: cvt_pkrtz returns __fp16x2 (not _Float16x2) -> keep packs
// as int and bit_cast at the builtin boundary. DPP to fetch lane+1 is
// row_shl:1 = 0x101 (row_shr pulls from LOWER lanes — would be silent wrong).

typedef float    f32x4 __attribute__((ext_vector_type(4)));
typedef _Float16 f16x2 __attribute__((ext_vector_type(2)));

#define S_LEN 2048
#define B_SZ  64
#define D_SZ  512
#define DIM   64
#define STRIDE ((size_t)(B_SZ * D_SZ))   // floats between consecutive s

// Branchless exact-GELU: 0.5*y*(1+erf(y/sqrt2)), erf via A&S 7.1.26 (|eps|<=1.5e-7).
__device__ __forceinline__ float gelu_exact(float y) {
    const float ax = fabsf(y) * 0.70710678118654752440f;     // |y|/sqrt(2)
    const float t  = __builtin_amdgcn_rcpf(fmaf(0.3275911f, ax, 1.0f));
    float p = fmaf(1.061405429f, t, -1.453152027f);
    p = fmaf(p, t, 1.421413741f);
    p = fmaf(p, t, -0.284496736f);
    p = fmaf(p, t, 0.254829592f);
    p *= t;
    const float e = __builtin_amdgcn_exp2f(-ax * ax * 1.44269504088896f);
    float er = fmaf(-p, e, 1.0f);                            // erf(|x|)
    er = copysignf(er, y);
    return 0.5f * y * (1.0f + er);
}

__device__ __forceinline__ int pkrtz(float a, float b) {
    return __builtin_bit_cast(int, __builtin_amdgcn_cvt_pkrtz(a, b));
}

// ---------------- Pass 1 (unchanged from round 9): LDS-broadcast GEMV.
__device__ __forceinline__ float gemv64(const f32x4* vv, const f32x4 (&w)[16],
                                        float base) {
    float a0 = base, a1 = 0.f, a2 = 0.f, a3 = 0.f;
    float a4 = 0.f, a5 = 0.f, a6 = 0.f, a7 = 0.f;
#pragma unroll
    for (int j = 0; j < 16; j += 2) {
        const f32x4 u0 = vv[j], u1 = vv[j + 1];
        a0 = fmaf(w[j].x,     u0.x, a0);
        a1 = fmaf(w[j].y,     u0.y, a1);
        a2 = fmaf(w[j].z,     u0.z, a2);
        a3 = fmaf(w[j].w,     u0.w, a3);
        a4 = fmaf(w[j + 1].x, u1.x, a4);
        a5 = fmaf(w[j + 1].y, u1.y, a5);
        a6 = fmaf(w[j + 1].z, u1.z, a6);
        a7 = fmaf(w[j + 1].w, u1.w, a7);
    }
    return ((a0 + a1) + (a2 + a3)) + ((a4 + a5) + (a6 + a7));
}

__global__ __launch_bounds__(64, 1) void bracket_pass1(
    const float* __restrict__ src, const float* __restrict__ W,
    const float* __restrict__ bias, float* __restrict__ zout)
{
    const int lane = threadIdx.x;
    const int ck   = blockIdx.x >> 9;          // 0..15 (128 s each)
    const int bb   = (blockIdx.x >> 3) & 63;
    const int hh   = blockIdx.x & 7;

    f32x4 w[16];
    {
        const float* wb = W + (size_t)(hh * DIM + lane) * (2 * DIM) + DIM;
#pragma unroll
        for (int i = 0; i < 16; ++i)
            asm volatile("global_load_dwordx4 %0, %1, off offset:%2"
                         : "=v"(w[i]) : "v"(wb), "i"(16 * i));
    }
    asm volatile("s_waitcnt vmcnt(0)" ::: "memory");
    __builtin_amdgcn_sched_barrier(0);

    const float bv = bias[hh * DIM + lane];

    __shared__ __align__(16) float xsl[2][DIM];   // 512 B ping-pong

    const float* sp = src  + (size_t)(ck * 128) * STRIDE + (size_t)bb * D_SZ + hh * DIM + lane;
    float*       zp = zout + (size_t)(ck * 128) * STRIDE + (size_t)bb * D_SZ + hh * DIM + lane;

    float x0 = sp[0], x1 = sp[STRIDE];
    const float* pp    = sp + 2 * STRIDE;
    const float* plast = sp + 127 * STRIDE;

#define P1STEP(cur, xc)                                                       \
    do {                                                                      \
        xsl[cur][lane] = xc;                   /* ds_write_b32 */             \
        const float xn = *pp;                  /* fire-and-forget prefetch */ \
        pp = (pp < plast) ? (pp + STRIDE) : plast;                            \
        const float y = gemv64((const f32x4*)xsl[cur], w, bv);                \
        *zp = y;                                                              \
        zp += STRIDE;                                                         \
        xc = xn;                                                              \
    } while (0)

    for (int i = 0; i < 128; i += 2) {
        P1STEP(0, x0);
        P1STEP(1, x1);
    }
#undef P1STEP
}

// ---------------- Pass 2: serial chain, f16-pair dot2 GEMV.
__device__ __forceinline__ float fdot2h(int pack, int wpk, float acc) {
#if __has_builtin(__builtin_amdgcn_fdot2)
    return __builtin_amdgcn_fdot2(__builtin_bit_cast(f16x2, pack),
                                  __builtin_bit_cast(f16x2, wpk), acc, false);
#else
    float d;
    asm("v_dot2_f32_f16 %0, %1, %2, %3"
        : "=v"(d)
        : "v"(__builtin_bit_cast(f16x2, pack)),
          "v"(__builtin_bit_cast(f16x2, wpk)), "v"(acc));
    return d;
#endif
}

// Batch m (16 pairs): readlanes of packed g-pairs from even lanes 32m+2j,
// fenced, then 16 dot2s. Pair k = 16m+j uses wp[k] = (Wc[d][2k], Wc[d][2k+1]).
#define DOT16(m)                                                              \
    do {                                                                      \
        const int t0  = __builtin_amdgcn_readlane(gpi, 32 * m + 0);           \
        const int t1  = __builtin_amdgcn_readlane(gpi, 32 * m + 2);           \
        const int t2  = __builtin_amdgcn_readlane(gpi, 32 * m + 4);           \
        const int t3  = __builtin_amdgcn_readlane(gpi, 32 * m + 6);           \
        const int t4  = __builtin_amdgcn_readlane(gpi, 32 * m + 8);           \
        const int t5  = __builtin_amdgcn_readlane(gpi, 32 * m + 10);          \
        const int t6  = __builtin_amdgcn_readlane(gpi, 32 * m + 12);          \
        const int t7  = __builtin_amdgcn_readlane(gpi, 32 * m + 14);          \
        const int t8  = __builtin_amdgcn_readlane(gpi, 32 * m + 16);          \
        const int t9  = __builtin_amdgcn_readlane(gpi, 32 * m + 18);          \
        const int t10 = __builtin_amdgcn_readlane(gpi, 32 * m + 20);          \
        const int t11 = __builtin_amdgcn_readlane(gpi, 32 * m + 22);          \
        const int t12 = __builtin_amdgcn_readlane(gpi, 32 * m + 24);          \
        const int t13 = __builtin_amdgcn_readlane(gpi, 32 * m + 26);          \
        const int t14 = __builtin_amdgcn_readlane(gpi, 32 * m + 28);          \
        const int t15 = __builtin_amdgcn_readlane(gpi, 32 * m + 30);          \
        __builtin_amdgcn_sched_barrier(0);                                    \
        a0 = fdot2h(t0,  wp[16 * m + 0],  a0);                                \
        a1 = fdot2h(t1,  wp[16 * m + 1],  a1);                                \
        a2 = fdot2h(t2,  wp[16 * m + 2],  a2);                                \
        a3 = fdot2h(t3,  wp[16 * m + 3],  a3);                                \
        a4 = fdot2h(t4,  wp[16 * m + 4],  a4);                                \
        a5 = fdot2h(t5,  wp[16 * m + 5],  a5);                                \
        a6 = fdot2h(t6,  wp[16 * m + 6],  a6);                                \
        a7 = fdot2h(t7,  wp[16 * m + 7],  a7);                                \
        a0 = fdot2h(t8,  wp[16 * m + 8],  a0);                                \
        a1 = fdot2h(t9,  wp[16 * m + 9],  a1);                                \
        a2 = fdot2h(t10, wp[16 * m + 10], a2);                                \
        a3 = fdot2h(t11, wp[16 * m + 11], a3);                                \
        a4 = fdot2h(t12, wp[16 * m + 12], a4);                                \
        a5 = fdot2h(t13, wp[16 * m + 13], a5);                                \
        a6 = fdot2h(t14, wp[16 * m + 14], a6);                                \
        a7 = fdot2h(t15, wp[16 * m + 15], a7);                                \
    } while (0)

__global__ __launch_bounds__(64, 1) void bracket_pass2(
    const float* __restrict__ src, const float* __restrict__ W,
    float* __restrict__ out)   // out holds z on entry; overwritten with result
{
    const int lane = threadIdx.x;
    const int bb   = blockIdx.x >> 3;
    const int hh   = blockIdx.x & 7;

    // Wc row fp32 via volatile asm (non-rematerializable), packed to f16x2
    // pairs stored as int: wp[k] = pack(Wc[d][2k], Wc[d][2k+1]).
    f32x4 w[16];
    {
        const float* wb = W + (size_t)(hh * DIM + lane) * (2 * DIM);
#pragma unroll
        for (int i = 0; i < 16; ++i)
            asm volatile("global_load_dwordx4 %0, %1, off offset:%2"
                         : "=v"(w[i]) : "v"(wb), "i"(16 * i));
    }
    asm volatile("s_waitcnt vmcnt(0)" ::: "memory");
    __builtin_amdgcn_sched_barrier(0);

    int wp[32];
#pragma unroll
    for (int j = 0; j < 16; ++j) {
        wp[2 * j]     = pkrtz(w[j].x, w[j].y);
        wp[2 * j + 1] = pkrtz(w[j].z, w[j].w);
    }

    const float* sp = src + (size_t)bb * D_SZ + hh * DIM + lane;
    float*       op = out + (size_t)bb * D_SZ + hh * DIM + lane;

    // Depth-8 prefetch pipelines (x from src, z from out).
    float xb[8], zb[8];
#pragma unroll
    for (int i = 0; i < 8; ++i) {
        xb[i] = sp[(size_t)i * STRIDE];
        zb[i] = op[(size_t)i * STRIDE];
    }
    const float* px = sp + 8 * STRIDE;
    const float* pz = op + 8 * STRIDE;

    float g = 0.0f;   // ctx_0 = 0

#define GEMV_STEP(i)                                                          \
    const int gi  = __float_as_int(g);                                        \
    /* even lane 2k fetches g[2k+1]: row_shl:1 = 0x101 (src lane = dest+1) */ \
    const int gsh = __builtin_amdgcn_mov_dpp(gi, 0x101, 0xf, 0xf, true);      \
    const int gpi = pkrtz(g, __int_as_float(gsh));                            \
    float a0 = zb[i], a1 = 0.f, a2 = 0.f, a3 = 0.f;                           \
    float a4 = 0.f, a5 = 0.f, a6 = 0.f, a7 = 0.f;                             \
    DOT16(0); DOT16(1);                                                       \
    const float y = ((a0 + a1) + (a2 + a3)) + ((a4 + a5) + (a6 + a7));        \
    g = gelu_exact(y);                                                        \
    *op = xb[i] + g;                                                          \
    op += STRIDE;

    // Main: 255 blocks of 8 steps with unconditional prefetch (max read 2047).
    for (int blk = 0; blk < 255; ++blk) {
#pragma unroll
        for (int i = 0; i < 8; ++i) {
            { GEMV_STEP(i); }
            xb[i] = *px;
            zb[i] = *pz;
            px += STRIDE;
            pz += STRIDE;
        }
    }
    // Epilogue: last 8 steps, no prefetch.
#pragma unroll
    for (int i = 0; i < 8; ++i) {
        { GEMV_STEP(i); }
    }
#undef GEMV_STEP
}

extern "C" void kernel_launch(void* const* d_in, const int* in_sizes, int n_in,
                              void* d_out, int out_size, void* d_ws, size_t ws_size,
                              hipStream_t stream) {
    const float* src = (const float*)d_in[0];
    const float* W   = (const float*)d_in[1];
    const float* b   = (const float*)d_in[2];
    float* out       = (float*)d_out;

    hipLaunchKernelGGL(bracket_pass1, dim3(B_SZ * 8 * 16), dim3(64), 0, stream,
                       src, W, b, out);
    hipLaunchKernelGGL(bracket_pass2, dim3(B_SZ * 8), dim3(64), 0, stream,
                       src, W, out);
}

// Round 14
// 648.717 us; speedup vs baseline: 2.2964x; 1.1415x over previous
//
#include <hip/hip_runtime.h>
#include <math.h>

// BracketNet: ctx_{s+1} = GELU_exact(Wc·ctx_s + (b + Wx·x_s)); out_s = x_s + ctx_{s+1}
// pass1: z = b + Wx·x, parallel, LDS-broadcast GEMV at 8 waves/SIMD (~190 us).
// pass2: serial chain, one wave per (b,h); f16-pair dot2 GEMV (round 13) plus
//        EXPLICIT async prefetch: all x/z loads + out stores are volatile-asm
//        vmem ops in strict program order, depth-4 slots, counted s_waitcnt
//        vmcnt(N) per step (T4/T14 pattern).
//
// Round-13 lesson: plain-C prefetch regs got SUNK by the compiler (VGPR=44
// can't hold the pipeline) -> every step exposed a full L2/HBM round-trip
// (~400 cyc of the 635). Halving GEMV issue (r11->r13) moved time only -5%,
// confirming latency-bound. Volatile-asm loads can't sink; counted vmcnt
// keeps 8 loads in flight across steps.

typedef float    f32x4 __attribute__((ext_vector_type(4)));
typedef _Float16 f16x2 __attribute__((ext_vector_type(2)));

#define S_LEN 2048
#define B_SZ  64
#define D_SZ  512
#define DIM   64
#define STRIDE ((size_t)(B_SZ * D_SZ))   // floats between consecutive s

// Branchless exact-GELU: 0.5*y*(1+erf(y/sqrt2)), erf via A&S 7.1.26 (|eps|<=1.5e-7).
__device__ __forceinline__ float gelu_exact(float y) {
    const float ax = fabsf(y) * 0.70710678118654752440f;     // |y|/sqrt(2)
    const float t  = __builtin_amdgcn_rcpf(fmaf(0.3275911f, ax, 1.0f));
    float p = fmaf(1.061405429f, t, -1.453152027f);
    p = fmaf(p, t, 1.421413741f);
    p = fmaf(p, t, -0.284496736f);
    p = fmaf(p, t, 0.254829592f);
    p *= t;
    const float e = __builtin_amdgcn_exp2f(-ax * ax * 1.44269504088896f);
    float er = fmaf(-p, e, 1.0f);                            // erf(|x|)
    er = copysignf(er, y);
    return 0.5f * y * (1.0f + er);
}

__device__ __forceinline__ int pkrtz(float a, float b) {
    return __builtin_bit_cast(int, __builtin_amdgcn_cvt_pkrtz(a, b));
}

// ---------------- Pass 1 (unchanged from round 9): LDS-broadcast GEMV.
__device__ __forceinline__ float gemv64(const f32x4* vv, const f32x4 (&w)[16],
                                        float base) {
    float a0 = base, a1 = 0.f, a2 = 0.f, a3 = 0.f;
    float a4 = 0.f, a5 = 0.f, a6 = 0.f, a7 = 0.f;
#pragma unroll
    for (int j = 0; j < 16; j += 2) {
        const f32x4 u0 = vv[j], u1 = vv[j + 1];
        a0 = fmaf(w[j].x,     u0.x, a0);
        a1 = fmaf(w[j].y,     u0.y, a1);
        a2 = fmaf(w[j].z,     u0.z, a2);
        a3 = fmaf(w[j].w,     u0.w, a3);
        a4 = fmaf(w[j + 1].x, u1.x, a4);
        a5 = fmaf(w[j + 1].y, u1.y, a5);
        a6 = fmaf(w[j + 1].z, u1.z, a6);
        a7 = fmaf(w[j + 1].w, u1.w, a7);
    }
    return ((a0 + a1) + (a2 + a3)) + ((a4 + a5) + (a6 + a7));
}

__global__ __launch_bounds__(64, 1) void bracket_pass1(
    const float* __restrict__ src, const float* __restrict__ W,
    const float* __restrict__ bias, float* __restrict__ zout)
{
    const int lane = threadIdx.x;
    const int ck   = blockIdx.x >> 9;          // 0..15 (128 s each)
    const int bb   = (blockIdx.x >> 3) & 63;
    const int hh   = blockIdx.x & 7;

    f32x4 w[16];
    {
        const float* wb = W + (size_t)(hh * DIM + lane) * (2 * DIM) + DIM;
#pragma unroll
        for (int i = 0; i < 16; ++i)
            asm volatile("global_load_dwordx4 %0, %1, off offset:%2"
                         : "=v"(w[i]) : "v"(wb), "i"(16 * i));
    }
    asm volatile("s_waitcnt vmcnt(0)" ::: "memory");
    __builtin_amdgcn_sched_barrier(0);

    const float bv = bias[hh * DIM + lane];

    __shared__ __align__(16) float xsl[2][DIM];   // 512 B ping-pong

    const float* sp = src  + (size_t)(ck * 128) * STRIDE + (size_t)bb * D_SZ + hh * DIM + lane;
    float*       zp = zout + (size_t)(ck * 128) * STRIDE + (size_t)bb * D_SZ + hh * DIM + lane;

    float x0 = sp[0], x1 = sp[STRIDE];
    const float* pp    = sp + 2 * STRIDE;
    const float* plast = sp + 127 * STRIDE;

#define P1STEP(cur, xc)                                                       \
    do {                                                                      \
        xsl[cur][lane] = xc;                   /* ds_write_b32 */             \
        const float xn = *pp;                  /* fire-and-forget prefetch */ \
        pp = (pp < plast) ? (pp + STRIDE) : plast;                            \
        const float y = gemv64((const f32x4*)xsl[cur], w, bv);                \
        *zp = y;                                                              \
        zp += STRIDE;                                                         \
        xc = xn;                                                              \
    } while (0)

    for (int i = 0; i < 128; i += 2) {
        P1STEP(0, x0);
        P1STEP(1, x1);
    }
#undef P1STEP
}

// ---------------- Pass 2: serial chain, f16-pair dot2 GEMV + counted-vmcnt
// volatile-asm prefetch pipeline.
__device__ __forceinline__ float fdot2h(int pack, int wpk, float acc) {
#if __has_builtin(__builtin_amdgcn_fdot2)
    return __builtin_amdgcn_fdot2(__builtin_bit_cast(f16x2, pack),
                                  __builtin_bit_cast(f16x2, wpk), acc, false);
#else
    float d;
    asm("v_dot2_f32_f16 %0, %1, %2, %3"
        : "=v"(d)
        : "v"(__builtin_bit_cast(f16x2, pack)),
          "v"(__builtin_bit_cast(f16x2, wpk)), "v"(acc));
    return d;
#endif
}

#define DOT16(m)                                                              \
    do {                                                                      \
        const int t0  = __builtin_amdgcn_readlane(gpi, 32 * m + 0);           \
        const int t1  = __builtin_amdgcn_readlane(gpi, 32 * m + 2);           \
        const int t2  = __builtin_amdgcn_readlane(gpi, 32 * m + 4);           \
        const int t3  = __builtin_amdgcn_readlane(gpi, 32 * m + 6);           \
        const int t4  = __builtin_amdgcn_readlane(gpi, 32 * m + 8);           \
        const int t5  = __builtin_amdgcn_readlane(gpi, 32 * m + 10);          \
        const int t6  = __builtin_amdgcn_readlane(gpi, 32 * m + 12);          \
        const int t7  = __builtin_amdgcn_readlane(gpi, 32 * m + 14);          \
        const int t8  = __builtin_amdgcn_readlane(gpi, 32 * m + 16);          \
        const int t9  = __builtin_amdgcn_readlane(gpi, 32 * m + 18);          \
        const int t10 = __builtin_amdgcn_readlane(gpi, 32 * m + 20);          \
        const int t11 = __builtin_amdgcn_readlane(gpi, 32 * m + 22);          \
        const int t12 = __builtin_amdgcn_readlane(gpi, 32 * m + 24);          \
        const int t13 = __builtin_amdgcn_readlane(gpi, 32 * m + 26);          \
        const int t14 = __builtin_amdgcn_readlane(gpi, 32 * m + 28);          \
        const int t15 = __builtin_amdgcn_readlane(gpi, 32 * m + 30);          \
        __builtin_amdgcn_sched_barrier(0);                                    \
        a0 = fdot2h(t0,  wp[16 * m + 0],  a0);                                \
        a1 = fdot2h(t1,  wp[16 * m + 1],  a1);                                \
        a2 = fdot2h(t2,  wp[16 * m + 2],  a2);                                \
        a3 = fdot2h(t3,  wp[16 * m + 3],  a3);                                \
        a4 = fdot2h(t4,  wp[16 * m + 4],  a4);                                \
        a5 = fdot2h(t5,  wp[16 * m + 5],  a5);                                \
        a6 = fdot2h(t6,  wp[16 * m + 6],  a6);                                \
        a7 = fdot2h(t7,  wp[16 * m + 7],  a7);                                \
        a0 = fdot2h(t8,  wp[16 * m + 8],  a0);                                \
        a1 = fdot2h(t9,  wp[16 * m + 9],  a1);                                \
        a2 = fdot2h(t10, wp[16 * m + 10], a2);                                \
        a3 = fdot2h(t11, wp[16 * m + 11], a3);                                \
        a4 = fdot2h(t12, wp[16 * m + 12], a4);                                \
        a5 = fdot2h(t13, wp[16 * m + 13], a5);                                \
        a6 = fdot2h(t14, wp[16 * m + 14], a6);                                \
        a7 = fdot2h(t15, wp[16 * m + 15], a7);                                \
    } while (0)

// Volatile-asm vmem: strict program order, cannot be sunk/reordered.
#define GLOAD(dst, ptr) \
    asm volatile("global_load_dword %0, %1, off" : "=v"(dst) : "v"(ptr))
#define GSTORE(val, ptr) \
    asm volatile("global_store_dword %1, %0, off" : : "v"(val), "v"(ptr) : "memory")

__global__ __launch_bounds__(64, 1) void bracket_pass2(
    const float* __restrict__ src, const float* __restrict__ W,
    float* __restrict__ out)   // out holds z on entry; overwritten with result
{
    const int lane = threadIdx.x;
    const int bb   = blockIdx.x >> 3;
    const int hh   = blockIdx.x & 7;

    // Wc row fp32 (pinned), packed to f16x2 pairs stored as int.
    f32x4 w[16];
    {
        const float* wb = W + (size_t)(hh * DIM + lane) * (2 * DIM);
#pragma unroll
        for (int i = 0; i < 16; ++i)
            asm volatile("global_load_dwordx4 %0, %1, off offset:%2"
                         : "=v"(w[i]) : "v"(wb), "i"(16 * i));
    }
    asm volatile("s_waitcnt vmcnt(0)" ::: "memory");
    __builtin_amdgcn_sched_barrier(0);

    int wp[32];
#pragma unroll
    for (int j = 0; j < 16; ++j) {
        wp[2 * j]     = pkrtz(w[j].x, w[j].y);
        wp[2 * j + 1] = pkrtz(w[j].z, w[j].w);
    }

    const float* sp = src + (size_t)bb * D_SZ + hh * DIM + lane;
    float*       op = out + (size_t)bb * D_SZ + hh * DIM + lane;  // store ptr
    const float* px = sp;                                         // x load ptr
    const float* pz = op;                                         // z load ptr

    float xb[4], zb[4];
    float g = 0.0f;   // ctx_0 = 0

    // Prologue: issue 8 loads in order x0,z0,x1,z1,x2,z2,x3,z3.
#pragma unroll
    for (int i = 0; i < 4; ++i) {
        GLOAD(xb[i], px); px += STRIDE;
        GLOAD(zb[i], pz); pz += STRIDE;
    }

    // Step = wait(slot loads done) -> GEMV -> gelu -> store -> issue s+4 loads.
    // vmcnt accounting (3 vmem/step: store, load x, load z):
    //   steady state: slot-i z load has 9 newer vmem ops when consumed -> vmcnt(9)
    //   first 4 steps (prologue fill): 6,7,8,9
    //   epilogue (no loads issued): 9,7,5,3
#define STEP_CORE(i)                                                          \
    do {                                                                      \
        const float zi = zb[i];                                               \
        const int gi  = __float_as_int(g);                                    \
        const int gsh = __builtin_amdgcn_mov_dpp(gi, 0x101, 0xf, 0xf, true);  \
        const int gpi = pkrtz(g, __int_as_float(gsh));                        \
        float a0 = zi, a1 = 0.f, a2 = 0.f, a3 = 0.f;                          \
        float a4 = 0.f, a5 = 0.f, a6 = 0.f, a7 = 0.f;                         \
        DOT16(0); DOT16(1);                                                   \
        const float y = ((a0 + a1) + (a2 + a3)) + ((a4 + a5) + (a6 + a7));    \
        g = gelu_exact(y);                                                    \
        const float r = xb[i] + g;                                            \
        GSTORE(r, op);                                                        \
        op += STRIDE;                                                         \
    } while (0)

#define STEPL(i, N)                                                           \
    do {                                                                      \
        asm volatile("s_waitcnt vmcnt(" #N ")");                              \
        __builtin_amdgcn_sched_barrier(0);                                    \
        STEP_CORE(i);                                                         \
        GLOAD(xb[i], px); px += STRIDE;                                       \
        GLOAD(zb[i], pz); pz += STRIDE;                                       \
    } while (0)

#define STEPE(i, N)                                                           \
    do {                                                                      \
        asm volatile("s_waitcnt vmcnt(" #N ")");                              \
        __builtin_amdgcn_sched_barrier(0);                                    \
        STEP_CORE(i);                                                         \
    } while (0)

    // Steps 0..3 (pipeline fill).
    STEPL(0, 6); STEPL(1, 7); STEPL(2, 8); STEPL(3, 9);
    // Steps 4..2043: 510 blocks of 4.
    for (int blk = 0; blk < 510; ++blk) {
        STEPL(0, 9); STEPL(1, 9); STEPL(2, 9); STEPL(3, 9);
    }
    // Steps 2044..2047 (drain, no new loads; last load was x/z[2047] at step 2043).
    STEPE(0, 9); STEPE(1, 7); STEPE(2, 5); STEPE(3, 3);

#undef STEPL
#undef STEPE
#undef STEP_CORE
}

extern "C" void kernel_launch(void* const* d_in, const int* in_sizes, int n_in,
                              void* d_out, int out_size, void* d_ws, size_t ws_size,
                              hipStream_t stream) {
    const float* src = (const float*)d_in[0];
    const float* W   = (const float*)d_in[1];
    const float* b   = (const float*)d_in[2];
    float* out       = (float*)d_out;

    hipLaunchKernelGGL(bracket_pass1, dim3(B_SZ * 8 * 16), dim3(64), 0, stream,
                       src, W, b, out);
    hipLaunchKernelGGL(bracket_pass2, dim3(B_SZ * 8), dim3(64), 0, stream,
                       src, W, out);
}